// Round 11
// baseline (307.200 us; speedup 1.0000x reference)
//
#include <hip/hip_runtime.h>
#include <math.h>

// ---------------------------------------------------------------------------
// TemporalGCN: 2-layer LSTM (per-node sequences) -> 2 GCN rounds -> edge MLP.
//
// R10 post-mortem: LDS-weight lstm was DS-INSTRUCTION bound: 64 scalar
// ds_read_b32/thread/step at ~5.8cyc => ~46us/layer floor; lstm1's in-kernel
// g-precompute added 768 more LDS reads -> 99us measured. Also ~90us of every
// total is harness d_ws poison fills (untouchable).
// R11 lstm redesign (SEQB=2, 800 blocks, 2 blocks/CU):
//  * weights via ds_read_b128, row-major [j][k] stride-68 pad: 16 instr/step,
//    even 8-lane/bank-quad spread = LDS BW floor (~85 B/cyc).
//  * h broadcast via v_readlane (VALU) -- Phase B redundant in every wave, so
//    lane k holds h[k]; ZERO h traffic on the DS pipe.
//  * each weight read feeds 2 seqs; G1 read in-loop prefetched 1 step ahead
//    (R8-proven); no other global ops in the t-loop.
//  * weights+gates > 64KB static -> dynamic LDS + hipFuncSetAttribute.
//  * k_xproj1 (R8 version) restored; lstm1 consumes G1 rows directly.
// All per-seq accumulation expressions preserved verbatim (absmax 0.0).
// ---------------------------------------------------------------------------

#define Hd   64
#define Ed   5
#define Fd   6
#define Bd   8
#define Wd   12
#define Nd   200
#define NSEQ (Bd*Nd)        // 1600 sequences (b,n)
#define NG   (4*Hd)         // 256 gate rows
#define NEDGE (Bd*Nd*Nd)    // 320000 edges
#define WSTRIDE 68          // padded weight row stride (floats); 272B, 16B-aligned
#define LNEPS 1e-5f

__device__ __forceinline__ float sigm(float x) { return 1.0f / (1.0f + __expf(-x)); }
__device__ __forceinline__ float tanh_fast(float x) {
  float ax = fabsf(x);
  float t  = __expf(-2.0f * ax);
  float r  = (1.0f - t) / (1.0f + t);
  return copysignf(r, x);
}
__device__ __forceinline__ float rlane(float v, int lane) {
  return __uint_as_float(__builtin_amdgcn_readlane(__float_as_uint(v), lane));
}

// --------------------------------------------------------------------------
// Prep (flat-index dispatch):
//  [0,16384)        Wt1[k][j]    = Wih1[j][k]
//  [16384,24576)    gcnWT[r][k][u]
//  [24576,25216)    epWT[r][e][u]
//  [25216,29312)    W1aT[k][n]
//  [29312,33408)    W1bT[k][n]
//  [33408,50816)    Whh0P[j*68+k] = Whh0[j*64+k] (pad k>=64 with 0)
//  [50816,68224)    Whh1P[j*68+k] = Whh1[j*64+k]
__global__ __launch_bounds__(256) void k_prep(
    const float* __restrict__ Wih1, const float* __restrict__ gcn_W,
    const float* __restrict__ ep_W, const float* __restrict__ W1,
    const float* __restrict__ Whh0, const float* __restrict__ Whh1,
    float* __restrict__ Wt1, float* __restrict__ gcnWT,
    float* __restrict__ epWT, float* __restrict__ W1aT,
    float* __restrict__ W1bT, float* __restrict__ Whh0P,
    float* __restrict__ Whh1P)
{
  int idx = blockIdx.x * 256 + threadIdx.x;
  if (idx < 16384) {
    int k = idx >> 8, j = idx & 255;
    Wt1[idx] = Wih1[j * Hd + k];
  } else if (idx < 24576) {
    int r0 = idx - 16384;
    int round = r0 >> 12, rem = r0 & 4095;
    int k = rem >> 6, u = rem & 63;
    gcnWT[r0] = gcn_W[round * 4096 + u * 64 + k];
  } else if (idx < 25216) {
    int r0 = idx - 24576;
    int round = r0 / 320, rem = r0 % 320;
    int e = rem >> 6, u = rem & 63;
    epWT[r0] = ep_W[round * 320 + u * Ed + e];
  } else if (idx < 29312) {
    int r0 = idx - 25216;
    int k = r0 >> 6, n = r0 & 63;
    W1aT[r0] = W1[n * 133 + k];
  } else if (idx < 33408) {
    int r0 = idx - 29312;
    int k = r0 >> 6, n = r0 & 63;
    W1bT[r0] = W1[n * 133 + 64 + k];
  } else if (idx < 50816) {
    int r0 = idx - 33408;
    int j = r0 / WSTRIDE, k = r0 % WSTRIDE;
    Whh0P[r0] = (k < Hd) ? Whh0[j * Hd + k] : 0.f;
  } else if (idx < 68224) {
    int r0 = idx - 50816;
    int j = r0 / WSTRIDE, k = r0 % WSTRIDE;
    Whh1P[r0] = (k < Hd) ? Whh1[j * Hd + k] : 0.f;
  }
}

// --------------------------------------------------------------------------
// LSTM layer 0. 800 blocks x 256 threads; block owns TWO sequences.
// Thread j = gate row j; weights from LDS via ds_read_b128 (stride-68 rows),
// each read feeds both seqs. h via v_readlane (every wave runs Phase B
// redundantly, so lane k holds h[k] for both seqs). One barrier per step;
// y history in LDS (dup-free wave-0 writes), stored coalesced after loop.
// Dynamic LDS: 17408 + 1024 + 144 + 1536 floats = 80,448 B -> 2 blocks/CU.
__global__ __launch_bounds__(256, 2) void k_lstm0(
    const float* __restrict__ nf,
    const float* __restrict__ Wih0, const float* __restrict__ bih0,
    const float* __restrict__ bhh0, const float* __restrict__ Whh0P,
    float* __restrict__ y0)                             // (NSEQ, W, H)
{
  extern __shared__ float smem[];
  float* w_lds = smem;                   // 17,408 floats (256 rows x 68)
  float* gates = smem + 17408;           // [2][2][256] = 1024
  float* x_sh  = gates + 1024;           // [2][12][6]  = 144
  float* y_sh  = x_sh + 144;             // [2][12][64] = 1536

  const int tid  = threadIdx.x;
  const int seq0 = blockIdx.x * 2;
  const int j = tid;
  const int u = tid & 63;

  {  // stage weights as flat float4 (coalesced; 17 per thread)
    const float4* wsrc = (const float4*)Whh0P;
    float4* wdst = (float4*)w_lds;
    for (int idx = tid; idx < 4352; idx += 256) wdst[idx] = wsrc[idx];
  }
  for (int idx = tid; idx < 2 * Wd * Fd; idx += 256) {
    int s = idx / (Wd * Fd); int rem = idx % (Wd * Fd);
    int t = rem / Fd;        int f   = rem % Fd;
    int seq = seq0 + s; int b = seq / Nd; int n = seq % Nd;
    x_sh[idx] = nf[((b * Wd + t) * Nd + n) * Fd + f];
  }

  float wx[Fd];
  #pragma unroll
  for (int f = 0; f < Fd; ++f) wx[f] = Wih0[j * Fd + f];
  const float bias = bih0[j] + bhh0[j];
  const int jt = j >> 6;                 // 0=i,1=f,2=g,3=o (wave-uniform)

  float h0v = 0.f, h1v = 0.f, c0 = 0.f, c1 = 0.f;
  __syncthreads();

  const float4* w4p = (const float4*)w_lds + j * (WSTRIDE / 4);

  for (int t = 0; t < Wd; ++t) {
    const float* xp0 = x_sh + (0 * Wd + t) * Fd;
    const float* xp1 = x_sh + (1 * Wd + t) * Fd;
    float as0[4] = {bias, 0.f, 0.f, 0.f};
    float as1[4] = {bias, 0.f, 0.f, 0.f};
    #pragma unroll
    for (int f = 0; f < Fd; ++f) as0[1] += xp0[f] * wx[f];
    #pragma unroll
    for (int f = 0; f < Fd; ++f) as1[1] += xp1[f] * wx[f];
    #pragma unroll
    for (int q = 0; q < 16; ++q) {
      float4 w4 = w4p[q];                          // ds_read_b128, reused 2x
      float d0 = rlane(h0v, 4 * q)     * w4.x + rlane(h0v, 4 * q + 1) * w4.y +
                 rlane(h0v, 4 * q + 2) * w4.z + rlane(h0v, 4 * q + 3) * w4.w;
      float d1 = rlane(h1v, 4 * q)     * w4.x + rlane(h1v, 4 * q + 1) * w4.y +
                 rlane(h1v, 4 * q + 2) * w4.z + rlane(h1v, 4 * q + 3) * w4.w;
      as0[q & 3] += d0;
      as1[q & 3] += d1;
    }
    float acc0 = (as0[0] + as0[1]) + (as0[2] + as0[3]);
    float acc1 = (as1[0] + as1[1]) + (as1[2] + as1[3]);
    gates[(t & 1) * 512 + j]       = (jt == 2) ? tanh_fast(acc0) : sigm(acc0);
    gates[(t & 1) * 512 + 256 + j] = (jt == 2) ? tanh_fast(acc1) : sigm(acc1);
    __syncthreads();                     // the ONLY barrier per step
    const float* gb = gates + (t & 1) * 512;
    {  // seq 0 (redundant in every wave -> lane k holds h[k])
      float iv = gb[u], fv = gb[64 + u], gv = gb[128 + u], ov = gb[192 + u];
      c0 = fv * c0 + iv * gv;
      h0v = ov * tanh_fast(c0);
    }
    {  // seq 1
      float iv = gb[256 + u], fv = gb[320 + u], gv = gb[384 + u], ov = gb[448 + u];
      c1 = fv * c1 + iv * gv;
      h1v = ov * tanh_fast(c1);
    }
    if (tid < Hd) {                      // wave 0 records history (no dups)
      y_sh[(0 * Wd + t) * 64 + u] = h0v;
      y_sh[(1 * Wd + t) * 64 + u] = h1v;
    }
  }
  __syncthreads();
  for (int idx = tid; idx < 2 * Wd * Hd; idx += 256) {
    int s = idx / (Wd * Hd), rem = idx % (Wd * Hd);
    y0[(seq0 + s) * (Wd * Hd) + rem] = y_sh[idx];   // coalesced
  }
}

// --------------------------------------------------------------------------
// G1 = y0 @ Wih1.T + (bih1+bhh1): (19200 x 64) @ (64 x 256).  (R8 version)
__global__ __launch_bounds__(256) void k_xproj1(
    const float* __restrict__ y0,    // rows = seq*12+t
    const float* __restrict__ Wt1,   // (64,256) transposed Wih1
    const float* __restrict__ bih1, const float* __restrict__ bhh1,
    float* __restrict__ G1)          // (19200, 256)
{
  __shared__ float ysh[64 * 65];
  __shared__ float osh[2 * 64 * 65];

  const int tid  = threadIdx.x;
  const int row0 = blockIdx.x * 64;
  for (int idx = tid; idx < 64 * 64; idx += 256) {
    int r = idx >> 6, k = idx & 63;
    ysh[r * 65 + k] = y0[(row0 + r) * Hd + k];
  }
  __syncthreads();

  const int w = __builtin_amdgcn_readfirstlane(tid >> 6);
  const int r = tid & 63;
  float acc[64];
  #pragma unroll
  for (int c = 0; c < 64; ++c) acc[c] = 0.f;

  const float* wbase = Wt1 + (w << 6);
  #pragma unroll 2
  for (int k = 0; k < 64; ++k) {
    float yv = ysh[r * 65 + k];
    const float* wk = wbase + k * NG;    // uniform address -> s_load
    #pragma unroll
    for (int c = 0; c < 64; ++c) acc[c] = fmaf(yv, wk[c], acc[c]);
  }
  #pragma unroll
  for (int c = 0; c < 64; ++c) acc[c] += bih1[(w << 6) + c] + bhh1[(w << 6) + c];

  #pragma unroll
  for (int p = 0; p < 2; ++p) {
    __syncthreads();
    if ((w >> 1) == p) {
      float* orow = osh + ((w & 1) * 64 + r) * 65;
      #pragma unroll
      for (int c = 0; c < 64; ++c) orow[c] = acc[c];
    }
    __syncthreads();
    for (int idx = tid; idx < 2 * 64 * 64; idx += 256) {
      int c  = idx & 127;
      int rr = idx >> 7;
      G1[(row0 + rr) * NG + p * 128 + c] =
          osh[((c >> 6) * 64 + rr) * 65 + (c & 63)];
    }
  }
}

// --------------------------------------------------------------------------
// LSTM layer 1 recurrence. 800 blocks x 256 threads, SEQB=2, same engine as
// k_lstm0; a0 comes from G1 (bias folded), prefetched one step ahead.
// Dynamic LDS: 17408 + 1024 floats = 73,728 B -> 2 blocks/CU.
__global__ __launch_bounds__(256, 2) void k_lstm1(
    const float* __restrict__ G1,
    const float* __restrict__ Whh1P,
    float* __restrict__ hout)        // (NSEQ, H)
{
  extern __shared__ float smem[];
  float* w_lds = smem;                   // 17,408 floats
  float* gates = smem + 17408;           // 1024

  const int tid  = threadIdx.x;
  const int seq0 = blockIdx.x * 2;
  const int j = tid;
  const int u = tid & 63;

  {
    const float4* wsrc = (const float4*)Whh1P;
    float4* wdst = (float4*)w_lds;
    for (int idx = tid; idx < 4352; idx += 256) wdst[idx] = wsrc[idx];
  }
  const int jt = j >> 6;
  float h0v = 0.f, h1v = 0.f, c0 = 0.f, c1 = 0.f;
  float gc0 = G1[((seq0 + 0) * Wd + 0) * NG + j];
  float gc1 = G1[((seq0 + 1) * Wd + 0) * NG + j];
  __syncthreads();

  const float4* w4p = (const float4*)w_lds + j * (WSTRIDE / 4);

  for (int t = 0; t < Wd; ++t) {
    float gn0 = (t + 1 < Wd) ? G1[((seq0 + 0) * Wd + t + 1) * NG + j] : 0.f;
    float gn1 = (t + 1 < Wd) ? G1[((seq0 + 1) * Wd + t + 1) * NG + j] : 0.f;
    float as0[4] = {gc0, 0.f, 0.f, 0.f};
    float as1[4] = {gc1, 0.f, 0.f, 0.f};
    #pragma unroll
    for (int q = 0; q < 16; ++q) {
      float4 w4 = w4p[q];
      float d0 = rlane(h0v, 4 * q)     * w4.x + rlane(h0v, 4 * q + 1) * w4.y +
                 rlane(h0v, 4 * q + 2) * w4.z + rlane(h0v, 4 * q + 3) * w4.w;
      float d1 = rlane(h1v, 4 * q)     * w4.x + rlane(h1v, 4 * q + 1) * w4.y +
                 rlane(h1v, 4 * q + 2) * w4.z + rlane(h1v, 4 * q + 3) * w4.w;
      as0[q & 3] += d0;
      as1[q & 3] += d1;
    }
    float acc0 = (as0[0] + as0[1]) + (as0[2] + as0[3]);
    float acc1 = (as1[0] + as1[1]) + (as1[2] + as1[3]);
    gates[(t & 1) * 512 + j]       = (jt == 2) ? tanh_fast(acc0) : sigm(acc0);
    gates[(t & 1) * 512 + 256 + j] = (jt == 2) ? tanh_fast(acc1) : sigm(acc1);
    __syncthreads();
    const float* gb = gates + (t & 1) * 512;
    {
      float iv = gb[u], fv = gb[64 + u], gv = gb[128 + u], ov = gb[192 + u];
      c0 = fv * c0 + iv * gv;
      h0v = ov * tanh_fast(c0);
    }
    {
      float iv = gb[256 + u], fv = gb[320 + u], gv = gb[384 + u], ov = gb[448 + u];
      c1 = fv * c1 + iv * gv;
      h1v = ov * tanh_fast(c1);
    }
    gc0 = gn0;
    gc1 = gn1;
  }
  if (tid < 128) {
    int s = tid >> 6;
    hout[(seq0 + s) * Hd + u] = (s == 0) ? h0v : h1v;
  }
}

// --------------------------------------------------------------------------
// Fused per-row node pipeline: wsum -> GCN r0 -> GCN r1 -> u/v precompute.
__global__ __launch_bounds__(256) void k_node(
    const float* __restrict__ ef,    const float* __restrict__ adj,
    const float* __restrict__ h0,
    const float* __restrict__ gcnWT, const float* __restrict__ gcn_b,
    const float* __restrict__ epWT,  const float* __restrict__ ep_b,
    const float* __restrict__ ln_g,  const float* __restrict__ ln_b,
    const float* __restrict__ W1aT,  const float* __restrict__ W1bT,
    const float* __restrict__ b1,
    float* __restrict__ uu, float* __restrict__ vt)
{
  __shared__ float ef_sh[Nd * Ed];
  __shared__ float adj_sh[Nd];
  __shared__ float red[4][6];
  __shared__ float w6[6];
  __shared__ float hcur[Hd];

  const int row = blockIdx.x;      // b*200+i
  const int b = row / Nd, i = row % Nd;
  const int tid = threadIdx.x;

  const float* efrow = ef + (size_t)(((b * Wd + (Wd - 1)) * Nd + i)) * (Nd * Ed);
  for (int idx = tid; idx < Nd * Ed; idx += 256) ef_sh[idx] = efrow[idx];
  const float* adjrow = adj + (b * Nd + i) * Nd;
  if (tid < Nd) adj_sh[tid] = adjrow[tid];
  if (tid < Hd) hcur[tid] = h0[row * Hd + tid];
  __syncthreads();

  float p[6] = {0.f, 0.f, 0.f, 0.f, 0.f, 0.f};
  if (tid < Nd) {
    float a = adj_sh[tid];
    p[5] = a;
    #pragma unroll
    for (int k = 0; k < Ed; ++k) p[k] = a * ef_sh[tid * Ed + k];
  }
  #pragma unroll
  for (int k = 0; k < 6; ++k) {
    float v = p[k];
    for (int off = 32; off > 0; off >>= 1) v += __shfl_down(v, off);
    p[k] = v;
  }
  if ((tid & 63) == 0) {
    #pragma unroll
    for (int k = 0; k < 6; ++k) red[tid >> 6][k] = p[k];
  }
  __syncthreads();
  if (tid < 6)
    w6[tid] = red[0][tid] + red[1][tid] + red[2][tid] + red[3][tid];
  __syncthreads();

  const int u = tid & 63;
  #pragma unroll
  for (int round = 0; round < 2; ++round) {
    float hnew = 0.f;
    if (tid < 64) {
      const float* gwT = gcnWT + round * 4096;   // [k][u]
      const float* ewT = epWT  + round * 320;    // [e][u]
      float acc = gcn_b[round * Hd + u] + w6[5] * ep_b[round * Hd + u];
      #pragma unroll
      for (int e = 0; e < Ed; ++e) acc += w6[e] * ewT[e * 64 + u];
      #pragma unroll 8
      for (int k = 0; k < Hd; ++k) acc += hcur[k] * gwT[k * 64 + u];

      float mu = acc;
      #pragma unroll
      for (int off = 1; off < 64; off <<= 1) mu += __shfl_xor(mu, off);
      mu *= (1.f / 64.f);
      float d = acc - mu;
      float var = d * d;
      #pragma unroll
      for (int off = 1; off < 64; off <<= 1) var += __shfl_xor(var, off);
      var *= (1.f / 64.f);
      float v = d * rsqrtf(var + LNEPS) * ln_g[round * Hd + u] + ln_b[round * Hd + u];
      hnew = fmaxf(v, 0.f);
    }
    __syncthreads();
    if (tid < 64) hcur[tid] = hnew;
    __syncthreads();
  }

  if (tid < 64) {
    float acc = b1[tid];
    #pragma unroll 8
    for (int k = 0; k < Hd; ++k) acc += hcur[k] * W1aT[k * 64 + tid];
    uu[row * Hd + tid] = acc;
  } else if (tid < 128) {
    const int n = tid - 64;
    float acc = 0.f;
    #pragma unroll 8
    for (int k = 0; k < Hd; ++k) acc += hcur[k] * W1bT[k * 64 + n];
    vt[n * NSEQ + row] = acc;
  }
}

// --------------------------------------------------------------------------
// Edge MLP: thread per edge. z1[64] in VGPRs; W1c/W2/W3/b2 wave-uniform ->
// scalar-pipe loads.
__global__ __launch_bounds__(256) void k_mlp(
    const float* __restrict__ ef,
    const float* __restrict__ u, const float* __restrict__ vt,
    const float* __restrict__ W1,
    const float* __restrict__ W2, const float* __restrict__ b2,
    const float* __restrict__ W3, const float* __restrict__ b3,
    float* __restrict__ out)
{
  const int idx = blockIdx.x * 256 + threadIdx.x;   // < 320000
  const int b   = idx / (Nd * Nd);
  const int rem = idx - b * Nd * Nd;
  const int i   = rem / Nd;
  const int jj  = rem - i * Nd;

  const float* e = ef + (((b * Wd + (Wd - 1)) * Nd + i) * Nd + jj) * Ed;
  float e5[Ed];
  #pragma unroll
  for (int q = 0; q < Ed; ++q) e5[q] = e[q];

  const float* ur = u + (b * Nd + i) * Hd;
  const int vcol = b * Nd + jj;

  float z1[64];
  #pragma unroll
  for (int k = 0; k < 64; ++k) {
    float acc = ur[k] + vt[k * NSEQ + vcol];
    const float* w1c = W1 + k * 133 + 128;
    #pragma unroll
    for (int q = 0; q < Ed; ++q) acc += e5[q] * w1c[q];
    z1[k] = fmaxf(acc, 0.f);
  }

  float logit = b3[0];
  #pragma unroll 4
  for (int o = 0; o < 32; ++o) {
    float a0 = b2[o], a1 = 0.f, a2 = 0.f, a3 = 0.f;
    const float* w2 = W2 + o * 64;
    #pragma unroll
    for (int k = 0; k < 64; k += 4) {
      a0 += w2[k]     * z1[k];
      a1 += w2[k + 1] * z1[k + 1];
      a2 += w2[k + 2] * z1[k + 2];
      a3 += w2[k + 3] * z1[k + 3];
    }
    float z2 = fmaxf((a0 + a1) + (a2 + a3), 0.f);
    logit += W3[o] * z2;
  }
  out[idx] = 1.f / (1.f + __expf(-logit));
}

// --------------------------------------------------------------------------
extern "C" void kernel_launch(void* const* d_in, const int* in_sizes, int n_in,
                              void* d_out, int out_size, void* d_ws, size_t ws_size,
                              hipStream_t stream) {
  (void)in_sizes; (void)n_in; (void)out_size; (void)ws_size;
  const float* nf   = (const float*)d_in[0];
  const float* ef   = (const float*)d_in[1];
  const float* adj  = (const float*)d_in[2];
  const float* Wih0 = (const float*)d_in[3];
  const float* Whh0 = (const float*)d_in[4];
  const float* bih0 = (const float*)d_in[5];
  const float* bhh0 = (const float*)d_in[6];
  const float* Wih1 = (const float*)d_in[7];
  const float* Whh1 = (const float*)d_in[8];
  const float* bih1 = (const float*)d_in[9];
  const float* bhh1 = (const float*)d_in[10];
  const float* gcnW = (const float*)d_in[11];
  const float* gcnB = (const float*)d_in[12];
  const float* epW  = (const float*)d_in[13];
  const float* epB  = (const float*)d_in[14];
  const float* lnG  = (const float*)d_in[15];
  const float* lnB  = (const float*)d_in[16];
  const float* W1   = (const float*)d_in[17];
  const float* b1   = (const float*)d_in[18];
  const float* W2   = (const float*)d_in[19];
  const float* b2   = (const float*)d_in[20];
  const float* W3   = (const float*)d_in[21];
  const float* b3   = (const float*)d_in[22];
  float* out = (float*)d_out;

  // Workspace layout (floats). Total ~6.5M floats = 26 MB.
  float* ws    = (float*)d_ws;
  float* y0    = ws;                        // 1,228,800
  float* G1    = y0    + 1228800;           // 4,915,200
  float* Wt1   = G1    + 4915200;           // 16,384
  float* h0    = Wt1   + 16384;             // 102,400
  float* uu    = h0    + 102400;            // 102,400
  float* vt    = uu    + 102400;            // 102,400
  float* gWT   = vt    + 102400;            // 8,192
  float* eWT   = gWT   + 8192;              // 640
  float* W1aT  = eWT   + 640;               // 4,096
  float* W1bT  = W1aT  + 4096;              // 4,096
  float* Whh0P = W1bT  + 4096;              // 17,408
  float* Whh1P = Whh0P + 17408;             // 17,408

  const int LDS0 = (17408 + 1024 + 144 + 1536) * 4;   // 80,448 B
  const int LDS1 = (17408 + 1024) * 4;                // 73,728 B
  hipFuncSetAttribute((const void*)k_lstm0,
      hipFuncAttributeMaxDynamicSharedMemorySize, LDS0);
  hipFuncSetAttribute((const void*)k_lstm1,
      hipFuncAttributeMaxDynamicSharedMemorySize, LDS1);

  k_prep  <<<267,  256, 0, stream>>>(Wih1, gcnW, epW, W1, Whh0, Whh1,
                                     Wt1, gWT, eWT, W1aT, W1bT, Whh0P, Whh1P);
  k_lstm0 <<<NSEQ/2, 256, LDS0, stream>>>(nf, Wih0, bih0, bhh0, Whh0P, y0);
  k_xproj1<<<300,  256, 0, stream>>>(y0, Wt1, bih1, bhh1, G1);
  k_lstm1 <<<NSEQ/2, 256, LDS1, stream>>>(G1, Whh1P, h0);
  k_node  <<<1600, 256, 0, stream>>>(ef, adj, h0, gWT, gcnB, eWT, epB,
                                     lnG, lnB, W1aT, W1bT, b1, uu, vt);
  k_mlp   <<<1250, 256, 0, stream>>>(ef, uu, vt, W1, W2, b2, W3, b3, out);
}